// Round 4
// baseline (234.664 us; speedup 1.0000x reference)
//
#include <hip/hip_runtime.h>
#include <hip/hip_bf16.h>

#define BB 4
#define HH 8
#define NN 4096
#define DD 64
#define RR 256

constexpr float SCALE = 0.35355339059327373f;  // 64^(-1/4)
constexpr float KEPS  = 0.001f;

typedef __attribute__((ext_vector_type(8)))  short short8;   // MFMA A/B frag
typedef __attribute__((ext_vector_type(16))) float f32x16;   // 32x32 MFMA C/D

#define MFMA(a, b, c) __builtin_amdgcn_mfma_f32_32x32x16_bf16(a, b, c, 0, 0, 0)

union S8U { short8 s; uint4 u; };

__device__ inline unsigned bfpk(float a, float b) {          // packed fp32x2 -> bf16x2 RTNE
    __hip_bfloat162 h = __float22bfloat162_rn(make_float2(a, b));
    return *reinterpret_cast<unsigned*>(&h);
}
__device__ inline unsigned short f2bfu(float f) {
    unsigned u = __float_as_uint(f);
    return (unsigned short)((u + 0x7fffu + ((u >> 16) & 1u)) >> 16);
}
__device__ inline f32x16 fz16() {
    f32x16 z;
#pragma unroll
    for (int e = 0; e < 16; ++e) z[e] = 0.f;
    return z;
}

// ---------------------------------------------------------------------------
// prep: proj fp32 -> bf16 row-major [256][64] (one b128-frag read per use later)
// ---------------------------------------------------------------------------
__global__ __launch_bounds__(256)
void prep_proj(const float* __restrict__ proj, unsigned short* __restrict__ projb)
{
    const int i = (blockIdx.x * 256 + threadIdx.x) * 4;
    const float4 v = *(const float4*)(proj + i);
    uint2 o; o.x = bfpk(v.x, v.y); o.y = bfpk(v.z, v.w);
    *(uint2*)(projb + i) = o;
}

// ---------------------------------------------------------------------------
// Kernel 1 (zero LDS, zero barriers): per (bh, n-chunk 256, r-half 128):
//   GEMM1: phi C-tile (A=K direct-global, B=proj bf16 frags)  C: col=r=l31
//   epilogue: relu*scale*m+eps, ksum, *m, pack bf16, shfl_xor(32) half-swap
//   GEMM2: ctx += phi^T . V (A=swapped regs, B=V direct-global dword reads)
//   finish: coalesced fp32 atomics.
// MFMA 32x32x16 layouts: A[m=l31][k=hf*8+j], B[k=hf*8+j][col=l31],
//   C col=l31, row=(i&3)+8*(i>>2)+4*hf.
// grid (16*2, HH, BB) = 1024 blocks = 4/CU at __launch_bounds__(256,4).
// ---------------------------------------------------------------------------
__global__ __launch_bounds__(256, 4)
void pk_ctx_kernel(const float* __restrict__ Kmat, const float* __restrict__ Vmat,
                   const float* __restrict__ mask, const unsigned short* __restrict__ projb,
                   float* __restrict__ g_ctx, float* __restrict__ g_ksum)
{
    const int tid = threadIdx.x;
    const int w = tid >> 6, lane = tid & 63;
    const int l31 = lane & 31, hf = lane >> 5;
    const int b = blockIdx.z, h = blockIdx.y;
    const int bh = b * HH + h;
    const int nc = blockIdx.x >> 1, rhalf = blockIdx.x & 1;
    const int n0 = nc * 256;
    const int rg = rhalf * 128 + w * 32 + l31;        // this lane's r (GEMM1 B col)
    const long kvbase = ((long)bh * NN + n0) * DD;

    f32x16 cacc[2];
    cacc[0] = fz16(); cacc[1] = fz16();
    float ksum = 0.f;

#pragma unroll 2
    for (int sub = 0; sub < 8; ++sub) {
        const long nb = kvbase + (long)(sub * 32) * DD;
        // ---- K A-frags (direct global) + proj B-frags (bf16, 1 load each) ----
        short8 afr[4], pfr[4];
#pragma unroll
        for (int ks = 0; ks < 4; ++ks) {
            const int d0 = ks * 16 + hf * 8;
            const float4 a = *(const float4*)(Kmat + nb + (long)l31 * DD + d0);
            const float4 c = *(const float4*)(Kmat + nb + (long)l31 * DD + d0 + 4);
            S8U t; t.u = make_uint4(bfpk(a.x, a.y), bfpk(a.z, a.w),
                                    bfpk(c.x, c.y), bfpk(c.z, c.w));
            afr[ks] = t.s;
            pfr[ks] = *(const short8*)(projb + rg * DD + d0);
        }
        f32x16 p = fz16();
#pragma unroll
        for (int ks = 0; ks < 4; ++ks) p = MFMA(afr[ks], pfr[ks], p);

        // ---- epilogue: phi = relu(dot*scale*m)+eps; pm = phi*m; pack ----
        unsigned own[8];
#pragma unroll
        for (int g = 0; g < 4; ++g) {
            const float4 mg = *(const float4*)(mask + b * NN + n0 + sub * 32 + 8 * g + 4 * hf);
            float pm[4];
            {
                float phi0 = fmaxf(p[4*g+0] * (SCALE * mg.x), 0.f) + KEPS; ksum += phi0; pm[0] = phi0 * mg.x;
                float phi1 = fmaxf(p[4*g+1] * (SCALE * mg.y), 0.f) + KEPS; ksum += phi1; pm[1] = phi1 * mg.y;
                float phi2 = fmaxf(p[4*g+2] * (SCALE * mg.z), 0.f) + KEPS; ksum += phi2; pm[2] = phi2 * mg.z;
                float phi3 = fmaxf(p[4*g+3] * (SCALE * mg.w), 0.f) + KEPS; ksum += phi3; pm[3] = phi3 * mg.w;
            }
            own[2*g]   = bfpk(pm[0], pm[1]);
            own[2*g+1] = bfpk(pm[2], pm[3]);
        }
        unsigned par[8];
#pragma unroll
        for (int q = 0; q < 8; ++q) par[q] = (unsigned)__shfl_xor((int)own[q], 32, 64);

        // ---- GEMM2: ctx += phi^T . V ----
#pragma unroll
        for (int kk = 0; kk < 2; ++kk) {
            S8U a;
            if (hf == 0) a.u = make_uint4(own[4*kk],   own[4*kk+1], par[4*kk],   par[4*kk+1]);
            else         a.u = make_uint4(par[4*kk+2], par[4*kk+3], own[4*kk+2], own[4*kk+3]);
#pragma unroll
            for (int dt = 0; dt < 2; ++dt) {
                const float* vp = Vmat + nb + (long)(kk * 16 + hf * 8) * DD + dt * 32 + l31;
                float f[8];
#pragma unroll
                for (int j = 0; j < 8; ++j) f[j] = vp[(long)j * DD];
                S8U vv; vv.u = make_uint4(bfpk(f[0], f[1]), bfpk(f[2], f[3]),
                                          bfpk(f[4], f[5]), bfpk(f[6], f[7]));
                cacc[dt] = MFMA(a.s, vv.s, cacc[dt]);
            }
        }
    }
    // ---- coalesced fp32 atomics ----
    const int rrow0 = rhalf * 128 + w * 32;
#pragma unroll
    for (int dt = 0; dt < 2; ++dt)
#pragma unroll
        for (int i = 0; i < 16; ++i) {
            const int row = (i & 3) + 8 * (i >> 2) + 4 * hf;
            atomicAdd(g_ctx + ((long)bh * RR + rrow0 + row) * DD + dt * 32 + l31, cacc[dt][i]);
        }
    const float kst = ksum + __shfl_xor(ksum, 32, 64);
    if (hf == 0) atomicAdd(g_ksum + bh * RR + rrow0 + l31, kst);
}

// ---------------------------------------------------------------------------
// finalize: g_ctx fp32 [bh][r][d] -> ctb bf16 [bh][d][r] (B-operand friendly)
// grid (8, HH, BB) = 256 blocks; block handles 8 d-columns x 256 r.
// ---------------------------------------------------------------------------
__global__ __launch_bounds__(256)
void finalize_ctx(const float* __restrict__ g_ctx, unsigned short* __restrict__ ctb)
{
    __shared__ unsigned short lds[8][264];   // 264 stride: b128-aligned rows, conflict-free
    const int tid = threadIdx.x;
    const int bh = blockIdx.z * HH + blockIdx.y;
    const int dc = blockIdx.x * 8;
    const float4 a = *(const float4*)(g_ctx + ((long)bh * RR + tid) * DD + dc);
    const float4 c = *(const float4*)(g_ctx + ((long)bh * RR + tid) * DD + dc + 4);
    const float f[8] = {a.x, a.y, a.z, a.w, c.x, c.y, c.z, c.w};
#pragma unroll
    for (int j = 0; j < 8; ++j) lds[j][tid] = f2bfu(f[j]);
    __syncthreads();
    const int j = tid >> 5, r0 = (tid & 31) * 8;
    const uint4 v = *(const uint4*)&lds[j][r0];
    *(uint4*)(ctb + ((long)bh * DD + dc + j) * RR + r0) = v;
}

// ---------------------------------------------------------------------------
// Kernel 2 (LDS = ksum only, 1 barrier): per (bh, n-chunk 128):
//   per wave (32 n): loop rt over 8 r-chunks:
//     GEMM3: C3[r][n] (A=proj bf16 frags, B=Q direct-global)  col=n=l31
//     epilogue: phi=relu(p)*scale+eps; s += phi*ksum[r]; pack; half-swap
//     GEMM4: out-acc += phi . ctx  (B=ctb bf16 [d][r] b128 frags)
//   finish: s via shfl_xor(32); sinv redistributed by __shfl; dword stores.
// grid (32, HH, BB) = 1024 blocks = 4/CU.
// ---------------------------------------------------------------------------
__global__ __launch_bounds__(256, 4)
void out_kernel(const float* __restrict__ Qmat, const unsigned short* __restrict__ projb,
                const unsigned short* __restrict__ ctb, const float* __restrict__ g_ksum,
                float* __restrict__ out)
{
    __shared__ float ks_lds[RR];
    const int tid = threadIdx.x;
    const int w = tid >> 6, lane = tid & 63;
    const int l31 = lane & 31, hf = lane >> 5;
    const int bh = blockIdx.z * HH + blockIdx.y;
    const int n0 = blockIdx.x * 128;
    const int nl = w * 32 + l31;                     // n-local (GEMM3 B col)
    const long qrow = ((long)bh * NN + n0 + nl) * DD;

    ks_lds[tid] = g_ksum[bh * RR + tid];
    __syncthreads();

    // Q B-frags resident (raw Q; SCALE folded into epilogue)
    short8 qfr[4];
#pragma unroll
    for (int ks = 0; ks < 4; ++ks) {
        const int d0 = ks * 16 + hf * 8;
        const float4 a = *(const float4*)(Qmat + qrow + d0);
        const float4 c = *(const float4*)(Qmat + qrow + d0 + 4);
        S8U t; t.u = make_uint4(bfpk(a.x, a.y), bfpk(a.z, a.w),
                                bfpk(c.x, c.y), bfpk(c.z, c.w));
        qfr[ks] = t.s;
    }

    f32x16 cacc[2];
    cacc[0] = fz16(); cacc[1] = fz16();
    float s_acc = 0.f;

#pragma unroll 2
    for (int rt = 0; rt < 8; ++rt) {
        f32x16 p = fz16();
#pragma unroll
        for (int ks = 0; ks < 4; ++ks) {
            const short8 af = *(const short8*)(projb + (rt * 32 + l31) * DD + ks * 16 + hf * 8);
            p = MFMA(af, qfr[ks], p);
        }
        unsigned own[8];
#pragma unroll
        for (int g = 0; g < 4; ++g) {
            const float4 kv = *(const float4*)&ks_lds[rt * 32 + 8 * g + 4 * hf];
            float ph[4];
            ph[0] = fmaxf(p[4*g+0], 0.f) * SCALE + KEPS; s_acc = fmaf(ph[0], kv.x, s_acc);
            ph[1] = fmaxf(p[4*g+1], 0.f) * SCALE + KEPS; s_acc = fmaf(ph[1], kv.y, s_acc);
            ph[2] = fmaxf(p[4*g+2], 0.f) * SCALE + KEPS; s_acc = fmaf(ph[2], kv.z, s_acc);
            ph[3] = fmaxf(p[4*g+3], 0.f) * SCALE + KEPS; s_acc = fmaf(ph[3], kv.w, s_acc);
            own[2*g]   = bfpk(ph[0], ph[1]);
            own[2*g+1] = bfpk(ph[2], ph[3]);
        }
        unsigned par[8];
#pragma unroll
        for (int q = 0; q < 8; ++q) par[q] = (unsigned)__shfl_xor((int)own[q], 32, 64);

#pragma unroll
        for (int kk = 0; kk < 2; ++kk) {
            S8U a;
            if (hf == 0) a.u = make_uint4(own[4*kk],   own[4*kk+1], par[4*kk],   par[4*kk+1]);
            else         a.u = make_uint4(par[4*kk+2], par[4*kk+3], own[4*kk+2], own[4*kk+3]);
#pragma unroll
            for (int dt = 0; dt < 2; ++dt) {
                const short8 bf = *(const short8*)(ctb + ((long)bh * DD + dt * 32 + l31) * RR
                                                       + rt * 32 + kk * 16 + hf * 8);
                cacc[dt] = MFMA(a.s, bf, cacc[dt]);
            }
        }
    }

    const float st = s_acc + __shfl_xor(s_acc, 32, 64);
    const float sinv = 1.0f / st;                    // valid for n-local-in-wave = l31
#pragma unroll
    for (int i = 0; i < 16; ++i) {
        const int row = (i & 3) + 8 * (i >> 2) + 4 * hf;
        const float sv = __shfl(sinv, row, 64);      // lanes 0..31 hold rows 0..31
#pragma unroll
        for (int dt = 0; dt < 2; ++dt)
            out[((long)bh * NN + n0 + w * 32 + row) * DD + dt * 32 + l31] = cacc[dt][i] * sv;
    }
}

// ---------------------------------------------------------------------------
extern "C" void kernel_launch(void* const* d_in, const int* in_sizes, int n_in,
                              void* d_out, int out_size, void* d_ws, size_t ws_size,
                              hipStream_t stream)
{
    const float* Q    = (const float*)d_in[0];
    const float* K    = (const float*)d_in[1];
    const float* V    = (const float*)d_in[2];
    const float* mask = (const float*)d_in[3];
    const float* proj = (const float*)d_in[4];
    float* out = (float*)d_out;

    float* g_ctx  = (float*)d_ws;                              // BH*RR*DD fp32 (2 MB)
    float* g_ksum = g_ctx + (size_t)BB * HH * RR * DD;         // BH*RR fp32 (32 KB)
    unsigned short* projb = (unsigned short*)(g_ksum + (size_t)BB * HH * RR);  // 32 KB
    unsigned short* ctb   = projb + (size_t)RR * DD;           // BH*DD*RR bf16 (1 MB)

    const size_t zbytes = ((size_t)BB * HH * RR * DD + (size_t)BB * HH * RR) * sizeof(float);
    hipMemsetAsync(d_ws, 0, zbytes, stream);

    prep_proj<<<dim3(RR * DD / 1024), 256, 0, stream>>>(proj, projb);

    dim3 g1((NN / 256) * 2, HH, BB);   // 1024 blocks
    pk_ctx_kernel<<<g1, 256, 0, stream>>>(K, V, mask, projb, g_ctx, g_ksum);

    dim3 gf(DD / 8, HH, BB);           // 256 blocks
    finalize_ctx<<<gf, 256, 0, stream>>>(g_ctx, ctb);

    dim3 g2(NN / 128, HH, BB);         // 1024 blocks
    out_kernel<<<g2, 256, 0, stream>>>(Q, projb, ctb, g_ksum, out);
}

// Round 5
// 221.477 us; speedup vs baseline: 1.0595x; 1.0595x over previous
//
#include <hip/hip_runtime.h>
#include <hip/hip_bf16.h>

#define BB 4
#define HH 8
#define NN 4096
#define DD 64
#define RR 256

constexpr float SCALE = 0.35355339059327373f;  // 64^(-1/4)
constexpr float KEPS  = 0.001f;

typedef __attribute__((ext_vector_type(8)))  short short8;   // MFMA A/B frag
typedef __attribute__((ext_vector_type(16))) float f32x16;   // 32x32 MFMA C/D

#define MFMA(a, b, c) __builtin_amdgcn_mfma_f32_32x32x16_bf16(a, b, c, 0, 0, 0)

union S8U { short8 s; uint4 u; };

__device__ inline unsigned bfpk(float a, float b) {          // fp32x2 -> bf16x2 RTNE
    __hip_bfloat162 h = __float22bfloat162_rn(make_float2(a, b));
    return *reinterpret_cast<unsigned*>(&h);
}
__device__ inline f32x16 fz16() {
    f32x16 z;
#pragma unroll
    for (int e = 0; e < 16; ++e) z[e] = 0.f;
    return z;
}

// ---------------------------------------------------------------------------
// prep: projb = bf16(proj * SCALE)  row-major [256][64]
// ---------------------------------------------------------------------------
__global__ __launch_bounds__(256)
void prep_proj(const float* __restrict__ proj, unsigned short* __restrict__ projb)
{
    const int i = (blockIdx.x * 256 + threadIdx.x) * 4;
    const float4 v = *(const float4*)(proj + i);
    uint2 o; o.x = bfpk(v.x * SCALE, v.y * SCALE); o.y = bfpk(v.z * SCALE, v.w * SCALE);
    *(uint2*)(projb + i) = o;
}

// ---------------------------------------------------------------------------
// Kernel 1: per (bh, n-chunk 256): double-buffered LDS staging of K*m, V*m
// (bf16, mask folded), 1 barrier per 32-row subtile.
//   GEMM1: phi = relu(Km . projS^T) + eps     C: col=r=l31 (per-wave 64 r)
//   half-swap shfl: phi C-regs -> B-operand frags (k=n) in registers
//   GEMM2: ctxT[d][r] += V^T . phi            A=V^T (scalar LDS reads), B=phi
// Epilogue: coalesced fp32 atomics into ctxT [bh][d][r]; ksum atomics.
// MFMA 32x32x16: A[m=l31][k=hf*8+j], B[k=hf*8+j][col=l31],
//                C col=l31, row=(i&3)+8*(i>>2)+4*hf.
// grid (16, HH, BB) = 512 blocks = 2/CU.
// ---------------------------------------------------------------------------
__global__ __launch_bounds__(256, 2)
void pk_ctx_kernel(const float* __restrict__ Kmat, const float* __restrict__ Vmat,
                   const float* __restrict__ mask, const unsigned short* __restrict__ projb,
                   float* __restrict__ g_ctxT, float* __restrict__ g_ksum)
{
    __shared__ unsigned short kt[2][32 * 72];   // K*m bf16, stride 72 (b128 frags)
    __shared__ unsigned short vt[2][32 * 68];   // V*m bf16, stride 68 (scalar col reads)

    const int tid = threadIdx.x;
    const int w = tid >> 6, lane = tid & 63;
    const int l31 = lane & 31, hf = lane >> 5;
    const int b = blockIdx.z, h = blockIdx.y;
    const int bh = b * HH + h;
    const int n0 = blockIdx.x * 256;

    const int sn = tid >> 3, sc = (tid & 7) * 8;       // staging row / col
    const long rowbase = ((long)bh * NN + n0 + sn) * DD + sc;
    const int  mbase   = b * NN + n0 + sn;

    // resident proj B-frags: col r = w*64 + rt*32 + l31
    short8 pfrag[2][4];
#pragma unroll
    for (int rt = 0; rt < 2; ++rt)
#pragma unroll
        for (int ks = 0; ks < 4; ++ks)
            pfrag[rt][ks] = *(const short8*)(projb + (w * 64 + rt * 32 + l31) * DD + ks * 16 + hf * 8);

    f32x16 acc[2][2];   // [mt(d-half)][rt(r-tile)]
    acc[0][0] = fz16(); acc[0][1] = fz16(); acc[1][0] = fz16(); acc[1][1] = fz16();
    float ksum[2] = {0.f, 0.f};

    auto stage = [&](int buf, int sub) {
        const long off = rowbase + (long)sub * 32 * DD;
        const float m = mask[mbase + sub * 32];
        const float4 ka = *(const float4*)(Kmat + off);
        const float4 kc = *(const float4*)(Kmat + off + 4);
        S8U t; t.u = make_uint4(bfpk(ka.x * m, ka.y * m), bfpk(ka.z * m, ka.w * m),
                                bfpk(kc.x * m, kc.y * m), bfpk(kc.z * m, kc.w * m));
        *(short8*)&kt[buf][sn * 72 + sc] = t.s;
        const float4 va = *(const float4*)(Vmat + off);
        const float4 vc = *(const float4*)(Vmat + off + 4);
        *(uint2*)&vt[buf][sn * 68 + sc]     = make_uint2(bfpk(va.x * m, va.y * m), bfpk(va.z * m, va.w * m));
        *(uint2*)&vt[buf][sn * 68 + sc + 4] = make_uint2(bfpk(vc.x * m, vc.y * m), bfpk(vc.z * m, vc.w * m));
    };

    stage(0, 0);
    __syncthreads();

    for (int sub = 0; sub < 8; ++sub) {
        const int buf = sub & 1;
        if (sub < 7) stage(buf ^ 1, sub + 1);

        // ---- GEMM1: phi C-tiles (A = K*m from LDS, B = resident projS) ----
        short8 afr[4];
#pragma unroll
        for (int ks = 0; ks < 4; ++ks)
            afr[ks] = *(const short8*)&kt[buf][l31 * 72 + ks * 16 + hf * 8];

        unsigned own[2][8];
#pragma unroll
        for (int rt = 0; rt < 2; ++rt) {
            f32x16 p = fz16();
#pragma unroll
            for (int ks = 0; ks < 4; ++ks) p = MFMA(afr[ks], pfrag[rt][ks], p);
#pragma unroll
            for (int g = 0; g < 4; ++g) {
                const float p0 = fmaxf(p[4*g+0], 0.f) + KEPS;
                const float p1 = fmaxf(p[4*g+1], 0.f) + KEPS;
                const float p2 = fmaxf(p[4*g+2], 0.f) + KEPS;
                const float p3 = fmaxf(p[4*g+3], 0.f) + KEPS;
                ksum[rt] += (p0 + p1) + (p2 + p3);
                own[rt][2*g]   = bfpk(p0, p1);
                own[rt][2*g+1] = bfpk(p2, p3);
            }
        }
        unsigned par[2][8];
#pragma unroll
        for (int rt = 0; rt < 2; ++rt)
#pragma unroll
            for (int q = 0; q < 8; ++q)
                par[rt][q] = (unsigned)__shfl_xor((int)own[rt][q], 32, 64);

        // ---- GEMM2: ctxT += V^T . phi ----
#pragma unroll
        for (int kk = 0; kk < 2; ++kk) {
            S8U bf[2];
#pragma unroll
            for (int rt = 0; rt < 2; ++rt) {
                if (hf == 0) bf[rt].u = make_uint4(own[rt][4*kk],   own[rt][4*kk+1],
                                                   par[rt][4*kk],   par[rt][4*kk+1]);
                else         bf[rt].u = make_uint4(par[rt][4*kk+2], par[rt][4*kk+3],
                                                   own[rt][4*kk+2], own[rt][4*kk+3]);
            }
#pragma unroll
            for (int mt = 0; mt < 2; ++mt) {
                short8 av;   // A = V^T[d = mt*32+l31][n = kk*16+hf*8+j]
#pragma unroll
                for (int j = 0; j < 8; ++j)
                    av[j] = (short)vt[buf][(kk * 16 + hf * 8 + j) * 68 + mt * 32 + l31];
                acc[mt][0] = MFMA(av, bf[0].s, acc[mt][0]);
                acc[mt][1] = MFMA(av, bf[1].s, acc[mt][1]);
            }
        }
        __syncthreads();
    }

    // ---- epilogue: coalesced fp32 atomics, ctxT[bh][d][r] ----
#pragma unroll
    for (int mt = 0; mt < 2; ++mt)
#pragma unroll
        for (int rt = 0; rt < 2; ++rt)
#pragma unroll
            for (int i = 0; i < 16; ++i) {
                const int drow = mt * 32 + (i & 3) + 8 * (i >> 2) + 4 * hf;
                atomicAdd(g_ctxT + ((long)bh * DD + drow) * RR + w * 64 + rt * 32 + l31,
                          acc[mt][rt][i]);
            }
#pragma unroll
    for (int rt = 0; rt < 2; ++rt) {
        const float kst = ksum[rt] + __shfl_xor(ksum[rt], 32, 64);
        if (hf == 0) atomicAdd(g_ksum + bh * RR + w * 64 + rt * 32 + l31, kst);
    }
}

// ---------------------------------------------------------------------------
// finalize: ctb = bf16(g_ctxT), same [bh][d][r] layout (pure elementwise)
// ---------------------------------------------------------------------------
__global__ __launch_bounds__(256)
void finalize_ctx(const float* __restrict__ g_ctxT, unsigned short* __restrict__ ctb)
{
    const long i = ((long)blockIdx.x * 256 + threadIdx.x) * 8;
    const float4 a = *(const float4*)(g_ctxT + i);
    const float4 c = *(const float4*)(g_ctxT + i + 4);
    uint4 o = make_uint4(bfpk(a.x, a.y), bfpk(a.z, a.w), bfpk(c.x, c.y), bfpk(c.z, c.w));
    *(uint4*)(ctb + i) = o;
}

// ---------------------------------------------------------------------------
// Kernel 2: per (bh, n-chunk 128): projS staged to LDS once (1 barrier total);
//   per wave (32 n), loop rt over 8 r-chunks:
//     GEMM3: C3[r][n] (A=projS from LDS, B=Q resident)   col=n=l31
//     epilogue: phi=relu+eps; s += phi*ksum; half-swap -> A-frags
//     GEMM4: out += phi . ctx  (B=ctb [d][r] b128, prefetched 1 rt ahead)
// grid (32, HH, BB) = 1024 blocks = 4/CU.
// ---------------------------------------------------------------------------
__global__ __launch_bounds__(256, 4)
void out_kernel(const float* __restrict__ Qmat, const unsigned short* __restrict__ projb,
                const unsigned short* __restrict__ ctb, const float* __restrict__ g_ksum,
                float* __restrict__ out)
{
    __shared__ unsigned short pl[256 * 72];   // projS bf16, stride 72
    __shared__ float ks_lds[RR];

    const int tid = threadIdx.x;
    const int w = tid >> 6, lane = tid & 63;
    const int l31 = lane & 31, hf = lane >> 5;
    const int bh = blockIdx.z * HH + blockIdx.y;
    const int n0 = blockIdx.x * 128;
    const int nl = w * 32 + l31;              // this lane's n (GEMM3 B col)

    // stage projS -> LDS (coalesced uint4), ksum -> LDS
#pragma unroll
    for (int t = 0; t < 8; ++t) {
        const int u = tid + t * 256;          // uint4 index over 2048
        const uint4 v = ((const uint4*)projb)[u];
        *(uint4*)&pl[(u >> 3) * 72 + (u & 7) * 8] = v;
    }
    ks_lds[tid] = g_ksum[bh * RR + tid];

    // resident Q B-frags
    const long qrow = ((long)bh * NN + n0 + nl) * DD;
    short8 qfr[4];
#pragma unroll
    for (int ks = 0; ks < 4; ++ks) {
        const float4 a = *(const float4*)(Qmat + qrow + ks * 16 + hf * 8);
        const float4 c = *(const float4*)(Qmat + qrow + ks * 16 + hf * 8 + 4);
        S8U t; t.u = make_uint4(bfpk(a.x, a.y), bfpk(a.z, a.w), bfpk(c.x, c.y), bfpk(c.z, c.w));
        qfr[ks] = t.s;
    }
    __syncthreads();

    f32x16 cacc[2];
    cacc[0] = fz16(); cacc[1] = fz16();
    float s_acc = 0.f;

    // prefetch ctb frags for rt=0: [kk*2+dt]
    short8 cpre[4];
#pragma unroll
    for (int q = 0; q < 4; ++q)
        cpre[q] = *(const short8*)(ctb + ((long)bh * DD + (q & 1) * 32 + l31) * RR
                                       + (q >> 1) * 16 + hf * 8);

    for (int rt = 0; rt < 8; ++rt) {
        short8 cur[4];
#pragma unroll
        for (int q = 0; q < 4; ++q) cur[q] = cpre[q];
        if (rt < 7) {
#pragma unroll
            for (int q = 0; q < 4; ++q)
                cpre[q] = *(const short8*)(ctb + ((long)bh * DD + (q & 1) * 32 + l31) * RR
                                               + (rt + 1) * 32 + (q >> 1) * 16 + hf * 8);
        }
        // ---- GEMM3 ----
        f32x16 p = fz16();
#pragma unroll
        for (int ks = 0; ks < 4; ++ks) {
            const short8 af = *(const short8*)&pl[(rt * 32 + l31) * 72 + ks * 16 + hf * 8];
            p = MFMA(af, qfr[ks], p);
        }
        // ---- epilogue: phi, s ----
        unsigned own[8];
#pragma unroll
        for (int g = 0; g < 4; ++g) {
            const float4 kv = *(const float4*)&ks_lds[rt * 32 + 8 * g + 4 * hf];
            const float p0 = fmaxf(p[4*g+0], 0.f) + KEPS; s_acc = fmaf(p0, kv.x, s_acc);
            const float p1 = fmaxf(p[4*g+1], 0.f) + KEPS; s_acc = fmaf(p1, kv.y, s_acc);
            const float p2 = fmaxf(p[4*g+2], 0.f) + KEPS; s_acc = fmaf(p2, kv.z, s_acc);
            const float p3 = fmaxf(p[4*g+3], 0.f) + KEPS; s_acc = fmaf(p3, kv.w, s_acc);
            own[2*g]   = bfpk(p0, p1);
            own[2*g+1] = bfpk(p2, p3);
        }
        unsigned par[8];
#pragma unroll
        for (int q = 0; q < 8; ++q) par[q] = (unsigned)__shfl_xor((int)own[q], 32, 64);
        // ---- GEMM4 ----
#pragma unroll
        for (int kk = 0; kk < 2; ++kk) {
            S8U a;
            if (hf == 0) a.u = make_uint4(own[4*kk],   own[4*kk+1], par[4*kk],   par[4*kk+1]);
            else         a.u = make_uint4(par[4*kk+2], par[4*kk+3], own[4*kk+2], own[4*kk+3]);
            cacc[0] = MFMA(a.s, cur[kk * 2 + 0], cacc[0]);
            cacc[1] = MFMA(a.s, cur[kk * 2 + 1], cacc[1]);
        }
    }

    const float st = s_acc + __shfl_xor(s_acc, 32, 64);
    const float sinv = 1.0f / st;             // valid at lane l31 = n-local
#pragma unroll
    for (int i = 0; i < 16; ++i) {
        const int row = (i & 3) + 8 * (i >> 2) + 4 * hf;
        const float sv = __shfl(sinv, row, 64);
#pragma unroll
        for (int dt = 0; dt < 2; ++dt)
            out[((long)bh * NN + n0 + w * 32 + row) * DD + dt * 32 + l31] = cacc[dt][i] * sv;
    }
}

// ---------------------------------------------------------------------------
extern "C" void kernel_launch(void* const* d_in, const int* in_sizes, int n_in,
                              void* d_out, int out_size, void* d_ws, size_t ws_size,
                              hipStream_t stream)
{
    const float* Q    = (const float*)d_in[0];
    const float* K    = (const float*)d_in[1];
    const float* V    = (const float*)d_in[2];
    const float* mask = (const float*)d_in[3];
    const float* proj = (const float*)d_in[4];
    float* out = (float*)d_out;

    float* g_ctxT = (float*)d_ws;                               // BH*DD*RR fp32 (2 MB)
    float* g_ksum = g_ctxT + (size_t)BB * HH * DD * RR;         // BH*RR fp32 (32 KB)
    unsigned short* projb = (unsigned short*)(g_ksum + (size_t)BB * HH * RR);  // 32 KB
    unsigned short* ctb   = projb + (size_t)RR * DD;            // BH*DD*RR bf16 (1 MB)

    const size_t zbytes = ((size_t)BB * HH * DD * RR + (size_t)BB * HH * RR) * sizeof(float);
    hipMemsetAsync(d_ws, 0, zbytes, stream);

    prep_proj<<<dim3(RR * DD / 1024), 256, 0, stream>>>(proj, projb);

    dim3 g1(NN / 256, HH, BB);   // 512 blocks
    pk_ctx_kernel<<<g1, 256, 0, stream>>>(K, V, mask, projb, g_ctxT, g_ksum);

    finalize_ctx<<<dim3(BB * HH * DD * RR / 2048), 256, 0, stream>>>(g_ctxT, ctb);

    dim3 g2(NN / 128, HH, BB);   // 1024 blocks
    out_kernel<<<g2, 256, 0, stream>>>(Q, projb, ctb, g_ksum, out);
}

// Round 6
// 209.833 us; speedup vs baseline: 1.1183x; 1.0555x over previous
//
#include <hip/hip_runtime.h>
#include <hip/hip_bf16.h>

#define BB 4
#define HH 8
#define NN 4096
#define DD 64
#define RR 256

constexpr float SCALE = 0.35355339059327373f;  // 64^(-1/4)
constexpr float KEPS  = 0.001f;

typedef __attribute__((ext_vector_type(8)))  short short8;   // MFMA A/B frag
typedef __attribute__((ext_vector_type(16))) float f32x16;   // 32x32 MFMA C/D

#define MFMA(a, b, c) __builtin_amdgcn_mfma_f32_32x32x16_bf16(a, b, c, 0, 0, 0)

union S8U { short8 s; uint4 u; };

__device__ inline unsigned bfpk(float a, float b) {          // fp32x2 -> bf16x2 RTNE
    __hip_bfloat162 h = __float22bfloat162_rn(make_float2(a, b));
    return *reinterpret_cast<unsigned*>(&h);
}
__device__ inline f32x16 fz16() {
    f32x16 z;
#pragma unroll
    for (int e = 0; e < 16; ++e) z[e] = 0.f;
    return z;
}

// ---------------------------------------------------------------------------
// prep: projb = bf16(proj * SCALE)  row-major [256][64]  (32 KB: L1-resident)
// ---------------------------------------------------------------------------
__global__ __launch_bounds__(256)
void prep_proj(const float* __restrict__ proj, unsigned short* __restrict__ projb)
{
    const int i = (blockIdx.x * 256 + threadIdx.x) * 4;
    const float4 v = *(const float4*)(proj + i);
    uint2 o; o.x = bfpk(v.x * SCALE, v.y * SCALE); o.y = bfpk(v.z * SCALE, v.w * SCALE);
    *(uint2*)(projb + i) = o;
}

// ---------------------------------------------------------------------------
// Kernel 1: per (bh, n-chunk 256, r-half 128): double-buffered LDS K*m / V*m
// (bf16, mask folded), 1 barrier/subtile.
//   GEMM1: phi = relu(Km . projS^T) + eps    C col = r (32 r per wave)
//   register half-swap (shfl_xor 32): C-regs -> B-operand frags (k=n)
//   GEMM2: ctxT[d][r] += V^T . phi           A = V^T (scalar LDS reads)
// Epilogue: coalesced fp32 atomics into ctxT [bh][d][r] + ksum.
// MFMA 32x32x16: A[m=l31][k=hf*8+j], B[k=hf*8+j][col=l31],
//                C col=l31, row=(i&3)+8*(i>>2)+4*hf.
// grid (32, HH, BB) = 1024 blocks; lb(256,3) -> 3 blocks/CU, no spill.
// ---------------------------------------------------------------------------
__global__ __launch_bounds__(256, 3)
void pk_ctx_kernel(const float* __restrict__ Kmat, const float* __restrict__ Vmat,
                   const float* __restrict__ mask, const unsigned short* __restrict__ projb,
                   float* __restrict__ g_ctxT, float* __restrict__ g_ksum)
{
    __shared__ unsigned short kt[2][32 * 72];   // K*m bf16, stride 72 (b128 frags)
    __shared__ unsigned short vt[2][32 * 68];   // V*m bf16, stride 68 (scalar col reads)

    const int tid = threadIdx.x;
    const int w = tid >> 6, lane = tid & 63;
    const int l31 = lane & 31, hf = lane >> 5;
    const int b = blockIdx.z, h = blockIdx.y;
    const int bh = b * HH + h;
    const int nc = blockIdx.x >> 1, rhalf = blockIdx.x & 1;
    const int n0 = nc * 256;
    const int rg = rhalf * 128 + w * 32 + l31;         // this lane's r

    const int sn = tid >> 3, sc = (tid & 7) * 8;       // staging row / col
    const long rowbase = ((long)bh * NN + n0 + sn) * DD + sc;
    const int  mbase   = b * NN + n0 + sn;

    // resident proj B-frags for this wave's 32 r
    short8 pfrag[4];
#pragma unroll
    for (int ks = 0; ks < 4; ++ks)
        pfrag[ks] = *(const short8*)(projb + rg * DD + ks * 16 + hf * 8);

    f32x16 acc[2];          // [mt = d-half], col = r
    acc[0] = fz16(); acc[1] = fz16();
    float ksum = 0.f;

    auto stage = [&](int buf, int sub) {
        const long off = rowbase + (long)sub * 32 * DD;
        const float m = mask[mbase + sub * 32];
        const float4 ka = *(const float4*)(Kmat + off);
        const float4 kc = *(const float4*)(Kmat + off + 4);
        S8U t; t.u = make_uint4(bfpk(ka.x * m, ka.y * m), bfpk(ka.z * m, ka.w * m),
                                bfpk(kc.x * m, kc.y * m), bfpk(kc.z * m, kc.w * m));
        *(short8*)&kt[buf][sn * 72 + sc] = t.s;
        const float4 va = *(const float4*)(Vmat + off);
        const float4 vc = *(const float4*)(Vmat + off + 4);
        *(uint2*)&vt[buf][sn * 68 + sc]     = make_uint2(bfpk(va.x * m, va.y * m), bfpk(va.z * m, va.w * m));
        *(uint2*)&vt[buf][sn * 68 + sc + 4] = make_uint2(bfpk(vc.x * m, vc.y * m), bfpk(vc.z * m, vc.w * m));
    };

    stage(0, 0);
    __syncthreads();

    for (int sub = 0; sub < 8; ++sub) {
        const int buf = sub & 1;
        if (sub < 7) stage(buf ^ 1, sub + 1);

        // ---- GEMM1: phi C-tile ----
        short8 afr[4];
#pragma unroll
        for (int ks = 0; ks < 4; ++ks)
            afr[ks] = *(const short8*)&kt[buf][l31 * 72 + ks * 16 + hf * 8];
        f32x16 p = fz16();
#pragma unroll
        for (int ks = 0; ks < 4; ++ks) p = MFMA(afr[ks], pfrag[ks], p);

        unsigned own[8];
#pragma unroll
        for (int g = 0; g < 4; ++g) {
            const float p0 = fmaxf(p[4*g+0], 0.f) + KEPS;
            const float p1 = fmaxf(p[4*g+1], 0.f) + KEPS;
            const float p2 = fmaxf(p[4*g+2], 0.f) + KEPS;
            const float p3 = fmaxf(p[4*g+3], 0.f) + KEPS;
            ksum += (p0 + p1) + (p2 + p3);
            own[2*g]   = bfpk(p0, p1);
            own[2*g+1] = bfpk(p2, p3);
        }
        unsigned par[8];
#pragma unroll
        for (int q = 0; q < 8; ++q) par[q] = (unsigned)__shfl_xor((int)own[q], 32, 64);

        // ---- GEMM2: ctxT += V^T . phi ----
#pragma unroll
        for (int kk = 0; kk < 2; ++kk) {
            S8U bf;
            if (hf == 0) bf.u = make_uint4(own[4*kk],   own[4*kk+1], par[4*kk],   par[4*kk+1]);
            else         bf.u = make_uint4(par[4*kk+2], par[4*kk+3], own[4*kk+2], own[4*kk+3]);
#pragma unroll
            for (int mt = 0; mt < 2; ++mt) {
                short8 av;   // A = V^T[d = mt*32+l31][n = kk*16+hf*8+j]
#pragma unroll
                for (int j = 0; j < 8; ++j)
                    av[j] = (short)vt[buf][(kk * 16 + hf * 8 + j) * 68 + mt * 32 + l31];
                acc[mt] = MFMA(av, bf.s, acc[mt]);
            }
        }
        __syncthreads();
    }

    // ---- epilogue: coalesced fp32 atomics into ctxT[bh][d][r] ----
#pragma unroll
    for (int mt = 0; mt < 2; ++mt)
#pragma unroll
        for (int i = 0; i < 16; ++i) {
            const int drow = mt * 32 + (i & 3) + 8 * (i >> 2) + 4 * hf;
            atomicAdd(g_ctxT + ((long)bh * DD + drow) * RR + rhalf * 128 + w * 32 + l31,
                      acc[mt][i]);
        }
    const float kst = ksum + __shfl_xor(ksum, 32, 64);
    if (hf == 0) atomicAdd(g_ksum + bh * RR + rhalf * 128 + w * 32 + l31, kst);
}

// ---------------------------------------------------------------------------
// Kernel 2: per (bh, n-chunk 128). LDS = ksum only (1 KB, 1 barrier).
//   per wave (32 n), rt over 8 r-chunks:
//     GEMM3: C3[r][n]  (A = projb b128 global/L1, B = Q resident)  col=n=l31
//     epilogue: phi = relu+eps; s += phi*ksum; half-swap -> A-frags
//     GEMM4: out += phi . ctx  (B = ctxT fp32 global/L1, cvt inline)
// grid (32, HH, BB) = 1024 blocks; lb(256,3), no LDS pressure, no spill.
// ---------------------------------------------------------------------------
__global__ __launch_bounds__(256, 3)
void out_kernel(const float* __restrict__ Qmat, const unsigned short* __restrict__ projb,
                const float* __restrict__ g_ctxT, const float* __restrict__ g_ksum,
                float* __restrict__ out)
{
    __shared__ float ks_lds[RR];

    const int tid = threadIdx.x;
    const int w = tid >> 6, lane = tid & 63;
    const int l31 = lane & 31, hf = lane >> 5;
    const int bh = blockIdx.z * HH + blockIdx.y;
    const int n0 = blockIdx.x * 128;
    const int nl = w * 32 + l31;              // this lane's n (GEMM3 B col)

    ks_lds[tid] = g_ksum[bh * RR + tid];

    // resident Q B-frags (raw Q; SCALE lives in projb)
    const long qrow = ((long)bh * NN + n0 + nl) * DD;
    short8 qfr[4];
#pragma unroll
    for (int ks = 0; ks < 4; ++ks) {
        const float4 a = *(const float4*)(Qmat + qrow + ks * 16 + hf * 8);
        const float4 c = *(const float4*)(Qmat + qrow + ks * 16 + hf * 8 + 4);
        S8U t; t.u = make_uint4(bfpk(a.x, a.y), bfpk(a.z, a.w), bfpk(c.x, c.y), bfpk(c.z, c.w));
        qfr[ks] = t.s;
    }
    __syncthreads();

    f32x16 cacc[2];
    cacc[0] = fz16(); cacc[1] = fz16();
    float s_acc = 0.f;

    for (int rt = 0; rt < 8; ++rt) {
        // ---- GEMM3 (A-frags straight from L1-resident projb) ----
        f32x16 p = fz16();
#pragma unroll
        for (int ks = 0; ks < 4; ++ks) {
            const short8 af = *(const short8*)(projb + (rt * 32 + l31) * DD + ks * 16 + hf * 8);
            p = MFMA(af, qfr[ks], p);
        }
        // ---- epilogue: phi, s ----
        unsigned own[8];
#pragma unroll
        for (int g = 0; g < 4; ++g) {
            const float4 kv = *(const float4*)&ks_lds[rt * 32 + 8 * g + 4 * hf];
            const float p0 = fmaxf(p[4*g+0], 0.f) + KEPS; s_acc = fmaf(p0, kv.x, s_acc);
            const float p1 = fmaxf(p[4*g+1], 0.f) + KEPS; s_acc = fmaf(p1, kv.y, s_acc);
            const float p2 = fmaxf(p[4*g+2], 0.f) + KEPS; s_acc = fmaf(p2, kv.z, s_acc);
            const float p3 = fmaxf(p[4*g+3], 0.f) + KEPS; s_acc = fmaf(p3, kv.w, s_acc);
            own[2*g]   = bfpk(p0, p1);
            own[2*g+1] = bfpk(p2, p3);
        }
        unsigned par[8];
#pragma unroll
        for (int q = 0; q < 8; ++q) par[q] = (unsigned)__shfl_xor((int)own[q], 32, 64);

        // ---- GEMM4 (B-frags from ctxT fp32, packed inline) ----
#pragma unroll
        for (int kk = 0; kk < 2; ++kk) {
            S8U a;
            if (hf == 0) a.u = make_uint4(own[4*kk],   own[4*kk+1], par[4*kk],   par[4*kk+1]);
            else         a.u = make_uint4(par[4*kk+2], par[4*kk+3], own[4*kk+2], own[4*kk+3]);
#pragma unroll
            for (int dt = 0; dt < 2; ++dt) {
                const float* cp = g_ctxT + ((long)bh * DD + dt * 32 + l31) * RR
                                         + rt * 32 + kk * 16 + hf * 8;
                const float4 x = *(const float4*)cp;
                const float4 y = *(const float4*)(cp + 4);
                S8U bfr; bfr.u = make_uint4(bfpk(x.x, x.y), bfpk(x.z, x.w),
                                            bfpk(y.x, y.y), bfpk(y.z, y.w));
                cacc[dt] = MFMA(a.s, bfr.s, cacc[dt]);
            }
        }
    }

    const float st = s_acc + __shfl_xor(s_acc, 32, 64);
    const float sinv = 1.0f / st;             // valid at lane l31 = n-local-in-wave
#pragma unroll
    for (int i = 0; i < 16; ++i) {
        const int row = (i & 3) + 8 * (i >> 2) + 4 * hf;
        const float sv = __shfl(sinv, row, 64);
#pragma unroll
        for (int dt = 0; dt < 2; ++dt)
            out[((long)bh * NN + n0 + w * 32 + row) * DD + dt * 32 + l31] = cacc[dt][i] * sv;
    }
}

// ---------------------------------------------------------------------------
extern "C" void kernel_launch(void* const* d_in, const int* in_sizes, int n_in,
                              void* d_out, int out_size, void* d_ws, size_t ws_size,
                              hipStream_t stream)
{
    const float* Q    = (const float*)d_in[0];
    const float* K    = (const float*)d_in[1];
    const float* V    = (const float*)d_in[2];
    const float* mask = (const float*)d_in[3];
    const float* proj = (const float*)d_in[4];
    float* out = (float*)d_out;

    float* g_ctxT = (float*)d_ws;                               // BH*DD*RR fp32 (2 MB)
    float* g_ksum = g_ctxT + (size_t)BB * HH * DD * RR;         // BH*RR fp32 (32 KB)
    unsigned short* projb = (unsigned short*)(g_ksum + (size_t)BB * HH * RR);  // 32 KB

    const size_t zbytes = ((size_t)BB * HH * DD * RR + (size_t)BB * HH * RR) * sizeof(float);
    hipMemsetAsync(d_ws, 0, zbytes, stream);

    prep_proj<<<dim3(RR * DD / 1024), 256, 0, stream>>>(proj, projb);

    dim3 g1((NN / 256) * 2, HH, BB);   // 1024 blocks
    pk_ctx_kernel<<<g1, 256, 0, stream>>>(K, V, mask, projb, g_ctxT, g_ksum);

    dim3 g2(NN / 128, HH, BB);         // 1024 blocks
    out_kernel<<<g2, 256, 0, stream>>>(Q, projb, g_ctxT, g_ksum, out);
}